// Round 6
// baseline (368.322 us; speedup 1.0000x reference)
//
#include <hip/hip_runtime.h>

// MultiheadAttention: B=4, S=2048, D_MODEL=1024, H=16, D_K=64, fp32 in/out.
// Pipeline (bf16 MFMA, fp32 accum):
//   1. transpose4: W[K][N] f32 -> Wt[N][K] bf16 (all 4 weights, one launch)
//   2. convert3: q/k/v f32 -> bf16 in one dispatch (scratch: d_out holds q,k; Cv holds v)
//   3. gemm_qkv: Q,K,V projections in ONE dispatch. 256x128 tile, 8 waves,
//      3-buffer LDS deep pipeline, counted s_waitcnt vmcnt(6), setprio around MFMA,
//      pre-swizzled GLD source + XOR'd ds_read, bijective XCD swizzle.
//      V epilogue permutation = swap kv bits 2<->3 (matches 32x32 PV B-fragment).
//   4. attn: 32x32x16 MFMA, NEW: 64 q per wave (2 i-groups of 32) -> K/V ds_reads
//      SHARED across i-groups (16 b128 reads per 32 MFMA, 2x better than R3);
//      grid (64,8)=512 blocks halves total staging; reg-staged ds_write with SW
//      swizzle (R1-proven 0 bank conflicts); R1 one-barrier-per-tile cadence.
//   5. gemm_out: same GEMM core, 256 blocks = exactly 1 CU round.

#define DM 1024
#define SQL 2048

typedef __attribute__((ext_vector_type(4))) float floatx4;
typedef __attribute__((ext_vector_type(16))) float floatx16;
typedef __attribute__((ext_vector_type(8))) __bf16 bf16x8;
typedef __attribute__((ext_vector_type(4))) __bf16 bf16x4;

// swizzled LDS address (halves): 64-half rows, 8-half chunks, chunk XOR row&7
#define SW(row, chunk) (((row) << 6) + ((((chunk) ^ ((row) & 7))) << 3))

// async 16B global->LDS copy; lds base must be wave-uniform (lane writes base+lane*16B)
#define GLD(gaddr, laddr)                                                              \
  __builtin_amdgcn_global_load_lds(                                                    \
      (const __attribute__((address_space(1))) unsigned int*)(gaddr),                  \
      (__attribute__((address_space(3))) unsigned int*)(laddr), 16, 0, 0)

__device__ __forceinline__ unsigned short f2bf(float f) {
  unsigned int u = __float_as_uint(f);
  u += 0x7fffu + ((u >> 16) & 1u);   // RNE
  return (unsigned short)(u >> 16);
}

// pack two f32 -> bf16 pair via v_perm (round-half-up)
__device__ __forceinline__ unsigned int pack_bf(float lo, float hi) {
  unsigned int a = __float_as_uint(lo) + 0x8000u;
  unsigned int b = __float_as_uint(hi) + 0x8000u;
  return __builtin_amdgcn_perm(b, a, 0x07060302u);  // {b.hi16, a.hi16}
}

// ---------------- all-4 weight transpose: W[1024][1024] f32 -> Wt[1024][1024] bf16
__global__ __launch_bounds__(256) void transpose4_kernel(
    const float* __restrict__ w0, const float* __restrict__ w1,
    const float* __restrict__ w2, const float* __restrict__ w3,
    unsigned short* __restrict__ t0, unsigned short* __restrict__ t1,
    unsigned short* __restrict__ t2, unsigned short* __restrict__ t3) {
  __shared__ unsigned short t[64][65];
  int z = blockIdx.z;
  const float* W = (z == 0) ? w0 : (z == 1) ? w1 : (z == 2) ? w2 : w3;
  unsigned short* Wt = (z == 0) ? t0 : (z == 1) ? t1 : (z == 2) ? t2 : t3;
  int tid = threadIdx.x;
  int n0 = blockIdx.x * 64, k0 = blockIdx.y * 64;
  for (int u = 0; u < 16; u++) {
    int idx = u * 256 + tid;
    int k = idx >> 6, n = idx & 63;
    t[k][n] = f2bf(W[(size_t)(k0 + k) * DM + n0 + n]);
  }
  __syncthreads();
  for (int u = 0; u < 16; u++) {
    int idx = u * 256 + tid;
    int n = idx >> 6, k = idx & 63;
    Wt[(size_t)(n0 + n) * DM + k0 + k] = t[k][n];
  }
}

// ---------------- f32 -> bf16 convert, 3 x 8M elements in one dispatch
__global__ __launch_bounds__(256) void convert3_kernel(
    const float* __restrict__ s0, const float* __restrict__ s1,
    const float* __restrict__ s2, unsigned short* __restrict__ d0,
    unsigned short* __restrict__ d1, unsigned short* __restrict__ d2) {
  int z = blockIdx.y;
  const float* S = (z == 0) ? s0 : (z == 1) ? s1 : s2;
  unsigned short* D = (z == 0) ? d0 : (z == 1) ? d1 : d2;
  int t = blockIdx.x * 256 + threadIdx.x;
  for (int u = 0; u < 8; u++) {
    int i = (u << 18) + t;
    float4 vv = ((const float4*)S)[i];
    uint2 p;
    p.x = pack_bf(vv.x, vv.y);
    p.y = pack_bf(vv.z, vv.w);
    ((uint2*)D)[i] = p;
  }
}

// ---------------- deep-pipelined GEMM core: C[256 x 128] tile, K=1024, BK=64.
// 8 waves as 4M x 2N (64x64 per wave). 3 LDS buffers; staging for K-tile t+2 is
// issued during K-tile t into buffer (t+2)%3 -> never touches the active buffer.
// K-tile boundary: s_waitcnt vmcnt(6) + s_barrier (counted, never drained mid-loop).
__device__ __forceinline__ void gemm_core_256x128(
    const unsigned short* __restrict__ A, const unsigned short* __restrict__ Bt,
    int m0, int n0, unsigned short* lds_a, unsigned short* lds_b,
    floatx4 acc[4][4]) {
  int tid = threadIdx.x;
  int wave = tid >> 6, lane = tid & 63;
  int quad = lane >> 4, c16 = lane & 15;
  int wm = wave >> 1, wn = wave & 1;
  int r8 = lane >> 3, l8 = lane & 7;
  int xch = (l8 ^ r8) << 3;  // pre-swizzled source chunk offset (halves)

  int r7 = c16 & 7;
  int aoff0 = ((wm * 64 + c16) << 6) + ((quad ^ r7) << 3);
  int aoff1 = ((wm * 64 + c16) << 6) + (((4 + quad) ^ r7) << 3);
  int boff0 = ((wn * 64 + c16) << 6) + ((quad ^ r7) << 3);
  int boff1 = ((wn * 64 + c16) << 6) + (((4 + quad) ^ r7) << 3);

  int aq = wave * 4;
  int bq = wave * 2;

#define STG_A(bufp, kt, u) \
  GLD(&A[(size_t)(m0 + (aq + (u)) * 8 + r8) * DM + (kt) + xch], (bufp) + (aq + (u)) * 512)
#define STG_B(bufp, kt, u) \
  GLD(&Bt[(size_t)(n0 + (bq + (u)) * 8 + r8) * DM + (kt) + xch], (bufp) + (bq + (u)) * 512)

  const floatx4 fz = {0.f, 0.f, 0.f, 0.f};
#pragma unroll
  for (int i = 0; i < 4; i++)
#pragma unroll
    for (int j = 0; j < 4; j++) acc[i][j] = fz;

#pragma unroll
  for (int u = 0; u < 4; u++) STG_A(lds_a, 0, u);
  STG_B(lds_b, 0, 0);
  STG_B(lds_b, 0, 1);
#pragma unroll
  for (int u = 0; u < 4; u++) STG_A(lds_a + 16384, 64, u);
  STG_B(lds_b + 8192, 64, 0);
  STG_B(lds_b + 8192, 64, 1);

  int cur = 0;
#pragma unroll 1
  for (int t = 0; t < 16; ++t) {
    if (t < 15) asm volatile("s_waitcnt vmcnt(6)\n\ts_barrier" ::: "memory");
    else        asm volatile("s_waitcnt vmcnt(0)\n\ts_barrier" ::: "memory");

    const unsigned short* la = lds_a + cur * 16384;
    const unsigned short* lb = lds_b + cur * 8192;
    int stg = cur + 2;
    if (stg >= 3) stg -= 3;
    unsigned short* sa = lds_a + stg * 16384;
    unsigned short* sb = lds_b + stg * 8192;
    bool do_st = (t < 14);
    int kt2 = (t + 2) << 6;

    bf16x8 a_[2], b0[4], b1[4];

    // ---- phase 0: ks=0, i=0..1 (+ all B ks=0); stage A u0,u1
    a_[0] = *(const bf16x8*)&la[aoff0];
    a_[1] = *(const bf16x8*)&la[aoff0 + 1024];
    b0[0] = *(const bf16x8*)&lb[boff0];
    b0[1] = *(const bf16x8*)&lb[boff0 + 1024];
    b0[2] = *(const bf16x8*)&lb[boff0 + 2048];
    b0[3] = *(const bf16x8*)&lb[boff0 + 3072];
    if (do_st) { STG_A(sa, kt2, 0); STG_A(sa, kt2, 1); }
    __builtin_amdgcn_s_barrier();
    __builtin_amdgcn_s_setprio(1);
#pragma unroll
    for (int j = 0; j < 4; j++)
      acc[0][j] = __builtin_amdgcn_mfma_f32_16x16x32_bf16(a_[0], b0[j], acc[0][j], 0, 0, 0);
#pragma unroll
    for (int j = 0; j < 4; j++)
      acc[1][j] = __builtin_amdgcn_mfma_f32_16x16x32_bf16(a_[1], b0[j], acc[1][j], 0, 0, 0);
    __builtin_amdgcn_s_setprio(0);
    __builtin_amdgcn_s_barrier();

    // ---- phase 1: ks=0, i=2..3; stage A u2,u3
    a_[0] = *(const bf16x8*)&la[aoff0 + 2048];
    a_[1] = *(const bf16x8*)&la[aoff0 + 3072];
    if (do_st) { STG_A(sa, kt2, 2); STG_A(sa, kt2, 3); }
    __builtin_amdgcn_s_barrier();
    __builtin_amdgcn_s_setprio(1);
#pragma unroll
    for (int j = 0; j < 4; j++)
      acc[2][j] = __builtin_amdgcn_mfma_f32_16x16x32_bf16(a_[0], b0[j], acc[2][j], 0, 0, 0);
#pragma unroll
    for (int j = 0; j < 4; j++)
      acc[3][j] = __builtin_amdgcn_mfma_f32_16x16x32_bf16(a_[1], b0[j], acc[3][j], 0, 0, 0);
    __builtin_amdgcn_s_setprio(0);
    __builtin_amdgcn_s_barrier();

    // ---- phase 2: ks=1, i=0..1 (+ all B ks=1); stage B u0,u1
    a_[0] = *(const bf16x8*)&la[aoff1];
    a_[1] = *(const bf16x8*)&la[aoff1 + 1024];
    b1[0] = *(const bf16x8*)&lb[boff1];
    b1[1] = *(const bf16x8*)&lb[boff1 + 1024];
    b1[2] = *(const bf16x8*)&lb[boff1 + 2048];
    b1[3] = *(const bf16x8*)&lb[boff1 + 3072];
    if (do_st) { STG_B(sb, kt2, 0); STG_B(sb, kt2, 1); }
    __builtin_amdgcn_s_barrier();
    __builtin_amdgcn_s_setprio(1);
#pragma unroll
    for (int j = 0; j < 4; j++)
      acc[0][j] = __builtin_amdgcn_mfma_f32_16x16x32_bf16(a_[0], b1[j], acc[0][j], 0, 0, 0);
#pragma unroll
    for (int j = 0; j < 4; j++)
      acc[1][j] = __builtin_amdgcn_mfma_f32_16x16x32_bf16(a_[1], b1[j], acc[1][j], 0, 0, 0);
    __builtin_amdgcn_s_setprio(0);
    __builtin_amdgcn_s_barrier();

    // ---- phase 3: ks=1, i=2..3
    a_[0] = *(const bf16x8*)&la[aoff1 + 2048];
    a_[1] = *(const bf16x8*)&la[aoff1 + 3072];
    __builtin_amdgcn_s_barrier();
    __builtin_amdgcn_s_setprio(1);
#pragma unroll
    for (int j = 0; j < 4; j++)
      acc[2][j] = __builtin_amdgcn_mfma_f32_16x16x32_bf16(a_[0], b1[j], acc[2][j], 0, 0, 0);
#pragma unroll
    for (int j = 0; j < 4; j++)
      acc[3][j] = __builtin_amdgcn_mfma_f32_16x16x32_bf16(a_[1], b1[j], acc[3][j], 0, 0, 0);
    __builtin_amdgcn_s_setprio(0);

    cur = cur + 1;
    if (cur >= 3) cur = 0;
  }
#undef STG_A
#undef STG_B
}

// ---------------- batched QKV projection GEMM: 768 blocks (3 clean CU rounds)
// z=0: Qb = (Aq@wqt + bq)*qscale  (bf16 row-major)
// z=1: Kb =  Ak@wkt + bk          (bf16 row-major)
// z=2: Vt =  Av@wvt + bv          (bf16 [b,h,d,s], s-column = swap bits 2<->3 of s&15)
__global__ __launch_bounds__(512, 2) void gemm_qkv_kernel(
    const unsigned short* __restrict__ Aq, const unsigned short* __restrict__ Ak,
    const unsigned short* __restrict__ Av, const unsigned short* __restrict__ wqt,
    const unsigned short* __restrict__ wkt, const unsigned short* __restrict__ wvt,
    const float* __restrict__ bq, const float* __restrict__ bk,
    const float* __restrict__ bv, unsigned short* __restrict__ Qb,
    unsigned short* __restrict__ Kb, unsigned short* __restrict__ VtOut,
    float qscale) {
  __shared__ unsigned short lds_a[3 * 256 * 64];  // 96 KiB
  __shared__ unsigned short lds_b[3 * 128 * 64];  // 48 KiB

  int lin = blockIdx.x + (blockIdx.y << 3) + (blockIdx.z << 8);
  int swz = (lin & 7) * 96 + (lin >> 3);
  int z = swz >> 8, rem = swz & 255;
  int m0 = (rem >> 3) << 8;
  int n0 = (rem & 7) << 7;

  const unsigned short* A  = (z == 0) ? Aq : (z == 1) ? Ak : Av;
  const unsigned short* Bt = (z == 0) ? wqt : (z == 1) ? wkt : wvt;
  const float* bias = (z == 0) ? bq : (z == 1) ? bk : bv;

  floatx4 acc[4][4];
  gemm_core_256x128(A, Bt, m0, n0, lds_a, lds_b, acc);

  int tid = threadIdx.x;
  int wave = tid >> 6, lane = tid & 63;
  int quad = lane >> 4, c16 = lane & 15;
  int wm = wave >> 1, wn = wave & 1;

  float scale = (z == 0) ? qscale : 1.0f;
#pragma unroll
  for (int i = 0; i < 4; i++)
#pragma unroll
    for (int j = 0; j < 4; j++) {
      int gc = n0 + wn * 64 + j * 16 + c16;
      float bvv = bias[gc];
      float val[4];
#pragma unroll
      for (int r = 0; r < 4; r++) val[r] = (acc[i][j][r] + bvv) * scale;
      int gr0 = m0 + wm * 64 + i * 16 + quad * 4;
      if (z < 2) {
        unsigned short* O = (z == 0) ? Qb : Kb;
#pragma unroll
        for (int r = 0; r < 4; r++) O[(size_t)(gr0 + r) * DM + gc] = f2bf(val[r]);
      } else {
        // V transposed + kv-permuted: s stored at column c = s with bits 2<->3 swapped
        int hh = gc >> 6, dd = gc & 63;
        int bidx = gr0 >> 11, srow = gr0 & 2047;
        int s6 = srow & 63;   // low 2 bits 0
        int c6 = (s6 & 51) | ((s6 & 4) << 1) | ((s6 & 8) >> 1);
        int srowp = (srow & ~63) | c6;
        uint2 pk;
        pk.x = pack_bf(val[0], val[1]);
        pk.y = pack_bf(val[2], val[3]);
        *(uint2*)&VtOut[((size_t)(bidx * 16 + hh) * 64 + dd) * SQL + srowp] = pk;
      }
    }
}

// ---------------- output GEMM: out[8192][1024] f32 = Cv_bf16 @ wot^T + bo
__global__ __launch_bounds__(512, 2) void gemm_out_kernel(
    const unsigned short* __restrict__ A, const unsigned short* __restrict__ Bt,
    const float* __restrict__ bias, float* __restrict__ O) {
  __shared__ unsigned short lds_a[3 * 256 * 64];
  __shared__ unsigned short lds_b[3 * 128 * 64];

  int lin = blockIdx.x + (blockIdx.y << 3);
  int swz = (lin & 7) * 32 + (lin >> 3);
  int m0 = (swz >> 3) << 8;
  int n0 = (swz & 7) << 7;

  floatx4 acc[4][4];
  gemm_core_256x128(A, Bt, m0, n0, lds_a, lds_b, acc);

  int tid = threadIdx.x;
  int wave = tid >> 6, lane = tid & 63;
  int quad = lane >> 4, c16 = lane & 15;
  int wm = wave >> 1, wn = wave & 1;

#pragma unroll
  for (int i = 0; i < 4; i++)
#pragma unroll
    for (int j = 0; j < 4; j++) {
      int gc = n0 + wn * 64 + j * 16 + c16;
      float bvv = bias[gc];
      int gr0 = m0 + wm * 64 + i * 16 + quad * 4;
#pragma unroll
      for (int r = 0; r < 4; r++) O[(size_t)(gr0 + r) * DM + gc] = acc[i][j][r] + bvv;
    }
}

// ---------------- flash attention, S^T formulation, 32x32x16 MFMA, 64 q/wave.
// Per wave: 64 q rows as 2 i-groups of 32 (q = ig*32 + (lane&31)); hl = lane>>5.
// QK: S^T[kv][q] = mfma(A=K-rows, B=Q^T[ig]); K fragments SHARED across i-groups
//   -> 8 K ds_reads feed 16 QK MFMAs. C: col=q31, kv=(reg&3)+8*(reg>>2)+4hl (+32j).
// PV: O^T[d][q] = mfma(A=Vt-rows, B=P^T[ig]); V fragments shared -> 8 V reads
//   feed 16 PV MFMAs. V stored with kv bits 2<->3 swapped so QK C-regs ARE the
//   PV B-fragment in identity order.
// Staging: reg-prefetch + SW-swizzled ds_write (R1-proven, 0 bank conflicts),
// double-buffered, ONE __syncthreads per tile. Grid (64,8) = 512 blocks.
__global__ __launch_bounds__(256, 2) void attn_kernel(
    const unsigned short* __restrict__ Qb, const unsigned short* __restrict__ Kb,
    const unsigned short* __restrict__ Vt, unsigned short* __restrict__ Cv) {
  __shared__ unsigned short lds_k[2][64 * 64];   // [kv][d] swizzled
  __shared__ unsigned short lds_v[2][64 * 64];   // [d][kv-permuted] swizzled
  int tid = threadIdx.x;
  int wave = tid >> 6, lane = tid & 63;
  int q31 = lane & 31, hl = lane >> 5;
  int bh = blockIdx.x, qt = blockIdx.y;
  int b = bh >> 4, h = bh & 15;

  int sr0 = tid >> 3, sc = tid & 7;              // staging rows sr0, sr0+32
  const unsigned short* kbase = &Kb[(size_t)(b * SQL) * DM + h * 64 + sc * 8];
  const unsigned short* vbase = &Vt[(size_t)(bh * 64) * SQL + sc * 8];

  // Q fragments per i-group: lane holds Q[q][s*16 + hl*8 + 0..7], q = gr0+ig*32+q31
  int gr0 = b * SQL + qt * 256 + wave * 64;
  bf16x8 qf[2][4];
#pragma unroll
  for (int ig = 0; ig < 2; ig++)
#pragma unroll
    for (int s = 0; s < 4; s++)
      qf[ig][s] = *(const bf16x8*)&Qb[(size_t)(gr0 + ig * 32 + q31) * DM + h * 64 + s * 16 + hl * 8];

  const floatx16 fz16 = {0.f, 0.f, 0.f, 0.f, 0.f, 0.f, 0.f, 0.f,
                         0.f, 0.f, 0.f, 0.f, 0.f, 0.f, 0.f, 0.f};
  floatx16 o[2][2];  // [ig][dt]: col=q31, row d=(reg&3)+8*(reg>>2)+4hl+32*dt
  o[0][0] = fz16; o[0][1] = fz16; o[1][0] = fz16; o[1][1] = fz16;
  float l_[2] = {0.f, 0.f};

  // stage tile 0
#pragma unroll
  for (int u = 0; u < 2; u++) {
    int r = sr0 + u * 32;
    *(uint4*)&lds_k[0][SW(r, sc)] = *(const uint4*)&kbase[(size_t)r * DM];
    *(uint4*)&lds_v[0][SW(r, sc)] = *(const uint4*)&vbase[(size_t)r * SQL];
  }
  __syncthreads();

#pragma unroll 1
  for (int t = 0; t < 32; t++) {
    int cur = t & 1;
    // register prefetch of tile t+1
    uint4 kreg[2], vreg[2];
    if (t + 1 < 32) {
      int t1 = (t + 1) * 64;
#pragma unroll
      for (int u = 0; u < 2; u++) {
        int r = sr0 + u * 32;
        kreg[u] = *(const uint4*)&kbase[(size_t)(t1 + r) * DM];
        vreg[u] = *(const uint4*)&vbase[(size_t)r * SQL + t1];
      }
    }

    // ---- QK^T both i-groups (K fragments shared)
    floatx16 st[2][2];  // [ig][j]
    __builtin_amdgcn_s_setprio(1);
#pragma unroll
    for (int j = 0; j < 2; j++) {
      bf16x8 kf = *(const bf16x8*)&lds_k[cur][SW(j * 32 + q31, hl)];
      st[0][j] = __builtin_amdgcn_mfma_f32_32x32x16_bf16(kf, qf[0][0], fz16, 0, 0, 0);
      st[1][j] = __builtin_amdgcn_mfma_f32_32x32x16_bf16(kf, qf[1][0], fz16, 0, 0, 0);
    }
#pragma unroll
    for (int s = 1; s < 4; s++)
#pragma unroll
      for (int j = 0; j < 2; j++) {
        bf16x8 kf = *(const bf16x8*)&lds_k[cur][SW(j * 32 + q31, 2 * s + hl)];
        st[0][j] = __builtin_amdgcn_mfma_f32_32x32x16_bf16(kf, qf[0][s], st[0][j], 0, 0, 0);
        st[1][j] = __builtin_amdgcn_mfma_f32_32x32x16_bf16(kf, qf[1][s], st[1][j], 0, 0, 0);
      }
    __builtin_amdgcn_s_setprio(0);

    // ---- softmax + pack per i-group
    bf16x8 pb[2][2][2];  // [ig][j][s2]
#pragma unroll
    for (int ig = 0; ig < 2; ig++) {
#pragma unroll
      for (int j = 0; j < 2; j++)
#pragma unroll
        for (int r = 0; r < 16; r++) st[ig][j][r] = __builtin_amdgcn_exp2f(st[ig][j][r]);
      float p0 = 0.f, p1 = 0.f, p2 = 0.f, p3 = 0.f;
#pragma unroll
      for (int r = 0; r < 16; r += 2) {
        p0 += st[ig][0][r]; p1 += st[ig][0][r + 1];
        p2 += st[ig][1][r]; p3 += st[ig][1][r + 1];
      }
      l_[ig] += (p0 + p1) + (p2 + p3);
#pragma unroll
      for (int j = 0; j < 2; j++)
#pragma unroll
        for (int s2 = 0; s2 < 2; s2++) {
#pragma unroll
          for (int e = 0; e < 8; e++) pb[ig][j][s2][e] = (__bf16)st[ig][j][s2 * 8 + e];
        }
    }

    // ---- PV both i-groups (V fragments shared)
    __builtin_amdgcn_s_setprio(1);
#pragma unroll
    for (int dt = 0; dt < 2; dt++)
#pragma unroll
      for (int j = 0; j < 2; j++)
#pragma unroll
        for (int s2 = 0; s2 < 2; s2++) {
          bf16x8 av = *(const bf16x8*)&lds_v[cur][SW(dt * 32 + q31, j * 4 + s2 * 2 + hl)];
          o[0][dt] = __builtin_amdgcn_mfma_f32_32x32x16_bf16(av, pb[0][j][s2], o[0][dt], 0, 0, 0);
          o[1][dt] = __builtin_amdgcn_mfma_f32_32x32x16_bf16(av, pb[1][j][s2], o[1][dt], 0, 0, 0);
        }
    __builtin_amdgcn_s_setprio(0);

    // ---- write prefetched tile t+1
    if (t + 1 < 32) {
      int nxt = cur ^ 1;
#pragma unroll
      for (int u = 0; u < 2; u++) {
        int r = sr0 + u * 32;
        *(uint4*)&lds_k[nxt][SW(r, sc)] = kreg[u];
        *(uint4*)&lds_v[nxt][SW(r, sc)] = vreg[u];
      }
    }
    __syncthreads();
  }

#pragma unroll
  for (int ig = 0; ig < 2; ig++) {
    l_[ig] += __shfl_xor(l_[ig], 32);
    float inv = 1.f / l_[ig];
    int gr = gr0 + ig * 32 + q31;
#pragma unroll
    for (int dt = 0; dt < 2; dt++)
#pragma unroll
      for (int g = 0; g < 4; g++) {
        bf16x4 ov;
        ov[0] = (__bf16)(o[ig][dt][4 * g + 0] * inv);
        ov[1] = (__bf16)(o[ig][dt][4 * g + 1] * inv);
        ov[2] = (__bf16)(o[ig][dt][4 * g + 2] * inv);
        ov[3] = (__bf16)(o[ig][dt][4 * g + 3] * inv);
        int d0 = dt * 32 + g * 8 + hl * 4;
        *(bf16x4*)&Cv[(size_t)gr * DM + h * 64 + d0] = ov;
      }
  }
}

extern "C" void kernel_launch(void* const* d_in, const int* in_sizes, int n_in,
                              void* d_out, int out_size, void* d_ws, size_t ws_size,
                              hipStream_t stream) {
  const float* q  = (const float*)d_in[0];
  const float* k  = (const float*)d_in[1];
  const float* v  = (const float*)d_in[2];
  const float* wq = (const float*)d_in[3];
  const float* bq = (const float*)d_in[4];
  const float* wk = (const float*)d_in[5];
  const float* bk = (const float*)d_in[6];
  const float* wv = (const float*)d_in[7];
  const float* bv = (const float*)d_in[8];
  const float* wo = (const float*)d_in[9];
  const float* bo = (const float*)d_in[10];
  float* out = (float*)d_out;

  char* ws = (char*)d_ws;
  unsigned short* wqt = (unsigned short*)(ws + (size_t)0);
  unsigned short* wkt = (unsigned short*)(ws + ((size_t)2 << 20));
  unsigned short* wvt = (unsigned short*)(ws + ((size_t)4 << 20));
  unsigned short* wot = (unsigned short*)(ws + ((size_t)6 << 20));
  unsigned short* Qb  = (unsigned short*)(ws + ((size_t)8 << 20));
  unsigned short* Kb  = (unsigned short*)(ws + ((size_t)24 << 20));
  unsigned short* Vt  = (unsigned short*)(ws + ((size_t)40 << 20));
  unsigned short* Cv  = (unsigned short*)(ws + ((size_t)56 << 20));
  // bf16-A scratch: d_out (32 MiB, rewritten by gemm_out at the end) holds q,k; Cv holds v.
  unsigned short* Aq = (unsigned short*)d_out;
  unsigned short* Ak = (unsigned short*)d_out + ((size_t)8 << 20);
  unsigned short* Av = Cv;

  const float QSCALE = 0.125f * 1.44269504088896340736f;  // 1/sqrt(64) * log2(e)

  dim3 blk(256);
  transpose4_kernel<<<dim3(16, 16, 4), blk, 0, stream>>>(wq, wk, wv, wo, wqt, wkt, wvt, wot);
  convert3_kernel<<<dim3(1024, 3), blk, 0, stream>>>(q, k, v, Aq, Ak, Av);
  gemm_qkv_kernel<<<dim3(8, 32, 3), dim3(512), 0, stream>>>(Aq, Ak, Av, wqt, wkt, wvt,
                                                            bq, bk, bv, Qb, Kb, Vt, QSCALE);
  attn_kernel<<<dim3(64, 8), blk, 0, stream>>>(Qb, Kb, Vt, Cv);
  gemm_out_kernel<<<dim3(8, 32), dim3(512), 0, stream>>>(Cv, wot, bo, out);
}

// Round 7
// 340.742 us; speedup vs baseline: 1.0809x; 1.0809x over previous
//
#include <hip/hip_runtime.h>

// MultiheadAttention: B=4, S=2048, D_MODEL=1024, H=16, D_K=64, fp32 in/out.
// Pipeline (bf16 MFMA, fp32 accum):
//   1. prep: MERGED transpose4 + convert3 in ONE dispatch (4096 blocks):
//      blocks [0,3072): q/k/v f32 -> bf16; blocks [3072,4096): W -> Wt bf16.
//      Saves one launch and overlaps the L2-bound transpose under the HBM-bound
//      convert.
//   2. gemm_qkv: Q,K,V projections in ONE dispatch. 256x128 tile, 8 waves,
//      3-buffer LDS deep pipeline, counted s_waitcnt vmcnt(6), setprio around MFMA,
//      pre-swizzled GLD source + XOR'd ds_read, bijective XCD swizzle.
//      V epilogue permutation = swap kv bits 2<->3 (matches 32x32 PV B-fragment).
//   3. attn: best-measured version (R3, 84.1us): 32x32x16 MFMA, 32 q/wave,
//      grid (64,16), GLD staging with pre-swizzled source, 2-buffer K/V,
//      one __syncthreads per tile, setprio around MFMA clusters.
//   4. gemm_out: same GEMM core, 256 blocks = exactly 1 CU round.

#define DM 1024
#define SQL 2048

typedef __attribute__((ext_vector_type(4))) float floatx4;
typedef __attribute__((ext_vector_type(16))) float floatx16;
typedef __attribute__((ext_vector_type(8))) __bf16 bf16x8;
typedef __attribute__((ext_vector_type(4))) __bf16 bf16x4;

// swizzled LDS address (halves): 64-half rows, 8-half chunks, chunk XOR row&7
#define SW(row, chunk) (((row) << 6) + ((((chunk) ^ ((row) & 7))) << 3))

// async 16B global->LDS copy; lds base must be wave-uniform (lane writes base+lane*16B)
#define GLD(gaddr, laddr)                                                              \
  __builtin_amdgcn_global_load_lds(                                                    \
      (const __attribute__((address_space(1))) unsigned int*)(gaddr),                  \
      (__attribute__((address_space(3))) unsigned int*)(laddr), 16, 0, 0)

__device__ __forceinline__ unsigned short f2bf(float f) {
  unsigned int u = __float_as_uint(f);
  u += 0x7fffu + ((u >> 16) & 1u);   // RNE
  return (unsigned short)(u >> 16);
}

// pack two f32 -> bf16 pair via v_perm (round-half-up)
__device__ __forceinline__ unsigned int pack_bf(float lo, float hi) {
  unsigned int a = __float_as_uint(lo) + 0x8000u;
  unsigned int b = __float_as_uint(hi) + 0x8000u;
  return __builtin_amdgcn_perm(b, a, 0x07060302u);  // {b.hi16, a.hi16}
}

// ---------------- merged prep: convert (blocks 0..3071) + weight transpose (3072..4095)
__global__ __launch_bounds__(256) void prep_kernel(
    const float* __restrict__ s0, const float* __restrict__ s1,
    const float* __restrict__ s2, unsigned short* __restrict__ d0,
    unsigned short* __restrict__ d1, unsigned short* __restrict__ d2,
    const float* __restrict__ w0, const float* __restrict__ w1,
    const float* __restrict__ w2, const float* __restrict__ w3,
    unsigned short* __restrict__ t0, unsigned short* __restrict__ t1,
    unsigned short* __restrict__ t2, unsigned short* __restrict__ t3) {
  __shared__ unsigned short t[64][65];
  int bx = blockIdx.x;
  int tid = threadIdx.x;
  if (bx < 3072) {
    // ---- convert: q/k/v f32 -> bf16, 8M elements per z
    int z = bx >> 10, xb = bx & 1023;
    const float* S = (z == 0) ? s0 : (z == 1) ? s1 : s2;
    unsigned short* D = (z == 0) ? d0 : (z == 1) ? d1 : d2;
    int tt = xb * 256 + tid;
    for (int u = 0; u < 8; u++) {
      int i = (u << 18) + tt;
      float4 vv = ((const float4*)S)[i];
      uint2 p;
      p.x = pack_bf(vv.x, vv.y);
      p.y = pack_bf(vv.z, vv.w);
      ((uint2*)D)[i] = p;
    }
  } else {
    // ---- transpose: W[1024][1024] f32 -> Wt[1024][1024] bf16 (64x64 tiles)
    int tx = bx - 3072;
    int z = tx & 3, p = tx >> 2;
    int n0 = (p & 15) * 64, k0 = (p >> 4) * 64;
    const float* W = (z == 0) ? w0 : (z == 1) ? w1 : (z == 2) ? w2 : w3;
    unsigned short* Wt = (z == 0) ? t0 : (z == 1) ? t1 : (z == 2) ? t2 : t3;
    for (int u = 0; u < 16; u++) {
      int idx = u * 256 + tid;
      int k = idx >> 6, n = idx & 63;
      t[k][n] = f2bf(W[(size_t)(k0 + k) * DM + n0 + n]);
    }
    __syncthreads();
    for (int u = 0; u < 16; u++) {
      int idx = u * 256 + tid;
      int n = idx >> 6, k = idx & 63;
      Wt[(size_t)(n0 + n) * DM + k0 + k] = t[k][n];
    }
  }
}

// ---------------- deep-pipelined GEMM core: C[256 x 128] tile, K=1024, BK=64.
// 8 waves as 4M x 2N (64x64 per wave). 3 LDS buffers; staging for K-tile t+2 is
// issued during K-tile t into buffer (t+2)%3 -> never touches the active buffer.
// K-tile boundary: s_waitcnt vmcnt(6) + s_barrier (counted, never drained mid-loop).
__device__ __forceinline__ void gemm_core_256x128(
    const unsigned short* __restrict__ A, const unsigned short* __restrict__ Bt,
    int m0, int n0, unsigned short* lds_a, unsigned short* lds_b,
    floatx4 acc[4][4]) {
  int tid = threadIdx.x;
  int wave = tid >> 6, lane = tid & 63;
  int quad = lane >> 4, c16 = lane & 15;
  int wm = wave >> 1, wn = wave & 1;
  int r8 = lane >> 3, l8 = lane & 7;
  int xch = (l8 ^ r8) << 3;  // pre-swizzled source chunk offset (halves)

  int r7 = c16 & 7;
  int aoff0 = ((wm * 64 + c16) << 6) + ((quad ^ r7) << 3);
  int aoff1 = ((wm * 64 + c16) << 6) + (((4 + quad) ^ r7) << 3);
  int boff0 = ((wn * 64 + c16) << 6) + ((quad ^ r7) << 3);
  int boff1 = ((wn * 64 + c16) << 6) + (((4 + quad) ^ r7) << 3);

  int aq = wave * 4;
  int bq = wave * 2;

#define STG_A(bufp, kt, u) \
  GLD(&A[(size_t)(m0 + (aq + (u)) * 8 + r8) * DM + (kt) + xch], (bufp) + (aq + (u)) * 512)
#define STG_B(bufp, kt, u) \
  GLD(&Bt[(size_t)(n0 + (bq + (u)) * 8 + r8) * DM + (kt) + xch], (bufp) + (bq + (u)) * 512)

  const floatx4 fz = {0.f, 0.f, 0.f, 0.f};
#pragma unroll
  for (int i = 0; i < 4; i++)
#pragma unroll
    for (int j = 0; j < 4; j++) acc[i][j] = fz;

#pragma unroll
  for (int u = 0; u < 4; u++) STG_A(lds_a, 0, u);
  STG_B(lds_b, 0, 0);
  STG_B(lds_b, 0, 1);
#pragma unroll
  for (int u = 0; u < 4; u++) STG_A(lds_a + 16384, 64, u);
  STG_B(lds_b + 8192, 64, 0);
  STG_B(lds_b + 8192, 64, 1);

  int cur = 0;
#pragma unroll 1
  for (int t = 0; t < 16; ++t) {
    if (t < 15) asm volatile("s_waitcnt vmcnt(6)\n\ts_barrier" ::: "memory");
    else        asm volatile("s_waitcnt vmcnt(0)\n\ts_barrier" ::: "memory");

    const unsigned short* la = lds_a + cur * 16384;
    const unsigned short* lb = lds_b + cur * 8192;
    int stg = cur + 2;
    if (stg >= 3) stg -= 3;
    unsigned short* sa = lds_a + stg * 16384;
    unsigned short* sb = lds_b + stg * 8192;
    bool do_st = (t < 14);
    int kt2 = (t + 2) << 6;

    bf16x8 a_[2], b0[4], b1[4];

    // ---- phase 0: ks=0, i=0..1 (+ all B ks=0); stage A u0,u1
    a_[0] = *(const bf16x8*)&la[aoff0];
    a_[1] = *(const bf16x8*)&la[aoff0 + 1024];
    b0[0] = *(const bf16x8*)&lb[boff0];
    b0[1] = *(const bf16x8*)&lb[boff0 + 1024];
    b0[2] = *(const bf16x8*)&lb[boff0 + 2048];
    b0[3] = *(const bf16x8*)&lb[boff0 + 3072];
    if (do_st) { STG_A(sa, kt2, 0); STG_A(sa, kt2, 1); }
    __builtin_amdgcn_s_barrier();
    __builtin_amdgcn_s_setprio(1);
#pragma unroll
    for (int j = 0; j < 4; j++)
      acc[0][j] = __builtin_amdgcn_mfma_f32_16x16x32_bf16(a_[0], b0[j], acc[0][j], 0, 0, 0);
#pragma unroll
    for (int j = 0; j < 4; j++)
      acc[1][j] = __builtin_amdgcn_mfma_f32_16x16x32_bf16(a_[1], b0[j], acc[1][j], 0, 0, 0);
    __builtin_amdgcn_s_setprio(0);
    __builtin_amdgcn_s_barrier();

    // ---- phase 1: ks=0, i=2..3; stage A u2,u3
    a_[0] = *(const bf16x8*)&la[aoff0 + 2048];
    a_[1] = *(const bf16x8*)&la[aoff0 + 3072];
    if (do_st) { STG_A(sa, kt2, 2); STG_A(sa, kt2, 3); }
    __builtin_amdgcn_s_barrier();
    __builtin_amdgcn_s_setprio(1);
#pragma unroll
    for (int j = 0; j < 4; j++)
      acc[2][j] = __builtin_amdgcn_mfma_f32_16x16x32_bf16(a_[0], b0[j], acc[2][j], 0, 0, 0);
#pragma unroll
    for (int j = 0; j < 4; j++)
      acc[3][j] = __builtin_amdgcn_mfma_f32_16x16x32_bf16(a_[1], b0[j], acc[3][j], 0, 0, 0);
    __builtin_amdgcn_s_setprio(0);
    __builtin_amdgcn_s_barrier();

    // ---- phase 2: ks=1, i=0..1 (+ all B ks=1); stage B u0,u1
    a_[0] = *(const bf16x8*)&la[aoff1];
    a_[1] = *(const bf16x8*)&la[aoff1 + 1024];
    b1[0] = *(const bf16x8*)&lb[boff1];
    b1[1] = *(const bf16x8*)&lb[boff1 + 1024];
    b1[2] = *(const bf16x8*)&lb[boff1 + 2048];
    b1[3] = *(const bf16x8*)&lb[boff1 + 3072];
    if (do_st) { STG_B(sb, kt2, 0); STG_B(sb, kt2, 1); }
    __builtin_amdgcn_s_barrier();
    __builtin_amdgcn_s_setprio(1);
#pragma unroll
    for (int j = 0; j < 4; j++)
      acc[0][j] = __builtin_amdgcn_mfma_f32_16x16x32_bf16(a_[0], b1[j], acc[0][j], 0, 0, 0);
#pragma unroll
    for (int j = 0; j < 4; j++)
      acc[1][j] = __builtin_amdgcn_mfma_f32_16x16x32_bf16(a_[1], b1[j], acc[1][j], 0, 0, 0);
    __builtin_amdgcn_s_setprio(0);
    __builtin_amdgcn_s_barrier();

    // ---- phase 3: ks=1, i=2..3
    a_[0] = *(const bf16x8*)&la[aoff1 + 2048];
    a_[1] = *(const bf16x8*)&la[aoff1 + 3072];
    __builtin_amdgcn_s_barrier();
    __builtin_amdgcn_s_setprio(1);
#pragma unroll
    for (int j = 0; j < 4; j++)
      acc[2][j] = __builtin_amdgcn_mfma_f32_16x16x32_bf16(a_[0], b1[j], acc[2][j], 0, 0, 0);
#pragma unroll
    for (int j = 0; j < 4; j++)
      acc[3][j] = __builtin_amdgcn_mfma_f32_16x16x32_bf16(a_[1], b1[j], acc[3][j], 0, 0, 0);
    __builtin_amdgcn_s_setprio(0);

    cur = cur + 1;
    if (cur >= 3) cur = 0;
  }
#undef STG_A
#undef STG_B
}

// ---------------- batched QKV projection GEMM: 768 blocks (3 clean CU rounds)
// z=0: Qb = (Aq@wqt + bq)*qscale  (bf16 row-major)
// z=1: Kb =  Ak@wkt + bk          (bf16 row-major)
// z=2: Vt =  Av@wvt + bv          (bf16 [b,h,d,s], s-column = swap bits 2<->3 of s&15)
__global__ __launch_bounds__(512, 2) void gemm_qkv_kernel(
    const unsigned short* __restrict__ Aq, const unsigned short* __restrict__ Ak,
    const unsigned short* __restrict__ Av, const unsigned short* __restrict__ wqt,
    const unsigned short* __restrict__ wkt, const unsigned short* __restrict__ wvt,
    const float* __restrict__ bq, const float* __restrict__ bk,
    const float* __restrict__ bv, unsigned short* __restrict__ Qb,
    unsigned short* __restrict__ Kb, unsigned short* __restrict__ VtOut,
    float qscale) {
  __shared__ unsigned short lds_a[3 * 256 * 64];  // 96 KiB
  __shared__ unsigned short lds_b[3 * 128 * 64];  // 48 KiB

  int lin = blockIdx.x + (blockIdx.y << 3) + (blockIdx.z << 8);
  int swz = (lin & 7) * 96 + (lin >> 3);
  int z = swz >> 8, rem = swz & 255;
  int m0 = (rem >> 3) << 8;
  int n0 = (rem & 7) << 7;

  const unsigned short* A  = (z == 0) ? Aq : (z == 1) ? Ak : Av;
  const unsigned short* Bt = (z == 0) ? wqt : (z == 1) ? wkt : wvt;
  const float* bias = (z == 0) ? bq : (z == 1) ? bk : bv;

  floatx4 acc[4][4];
  gemm_core_256x128(A, Bt, m0, n0, lds_a, lds_b, acc);

  int tid = threadIdx.x;
  int wave = tid >> 6, lane = tid & 63;
  int quad = lane >> 4, c16 = lane & 15;
  int wm = wave >> 1, wn = wave & 1;

  float scale = (z == 0) ? qscale : 1.0f;
#pragma unroll
  for (int i = 0; i < 4; i++)
#pragma unroll
    for (int j = 0; j < 4; j++) {
      int gc = n0 + wn * 64 + j * 16 + c16;
      float bvv = bias[gc];
      float val[4];
#pragma unroll
      for (int r = 0; r < 4; r++) val[r] = (acc[i][j][r] + bvv) * scale;
      int gr0 = m0 + wm * 64 + i * 16 + quad * 4;
      if (z < 2) {
        unsigned short* O = (z == 0) ? Qb : Kb;
#pragma unroll
        for (int r = 0; r < 4; r++) O[(size_t)(gr0 + r) * DM + gc] = f2bf(val[r]);
      } else {
        // V transposed + kv-permuted: s stored at column c = s with bits 2<->3 swapped
        int hh = gc >> 6, dd = gc & 63;
        int bidx = gr0 >> 11, srow = gr0 & 2047;
        int s6 = srow & 63;   // low 2 bits 0
        int c6 = (s6 & 51) | ((s6 & 4) << 1) | ((s6 & 8) >> 1);
        int srowp = (srow & ~63) | c6;
        uint2 pk;
        pk.x = pack_bf(val[0], val[1]);
        pk.y = pack_bf(val[2], val[3]);
        *(uint2*)&VtOut[((size_t)(bidx * 16 + hh) * 64 + dd) * SQL + srowp] = pk;
      }
    }
}

// ---------------- output GEMM: out[8192][1024] f32 = Cv_bf16 @ wot^T + bo
__global__ __launch_bounds__(512, 2) void gemm_out_kernel(
    const unsigned short* __restrict__ A, const unsigned short* __restrict__ Bt,
    const float* __restrict__ bias, float* __restrict__ O) {
  __shared__ unsigned short lds_a[3 * 256 * 64];
  __shared__ unsigned short lds_b[3 * 128 * 64];

  int lin = blockIdx.x + (blockIdx.y << 3);
  int swz = (lin & 7) * 32 + (lin >> 3);
  int m0 = (swz >> 3) << 8;
  int n0 = (swz & 7) << 7;

  floatx4 acc[4][4];
  gemm_core_256x128(A, Bt, m0, n0, lds_a, lds_b, acc);

  int tid = threadIdx.x;
  int wave = tid >> 6, lane = tid & 63;
  int quad = lane >> 4, c16 = lane & 15;
  int wm = wave >> 1, wn = wave & 1;

#pragma unroll
  for (int i = 0; i < 4; i++)
#pragma unroll
    for (int j = 0; j < 4; j++) {
      int gc = n0 + wn * 64 + j * 16 + c16;
      float bvv = bias[gc];
      int gr0 = m0 + wm * 64 + i * 16 + quad * 4;
#pragma unroll
      for (int r = 0; r < 4; r++) O[(size_t)(gr0 + r) * DM + gc] = acc[i][j][r] + bvv;
    }
}

// ---------------- flash attention (best-measured: R3, 84.1us), 32x32x16 MFMA.
// Per wave: 32 q rows (q = lane&31, hl = lane>>5 selects d/kv half).
// QK: S^T[kv][q] = mfma(A=K-rows, B=Q^T); C: col=q (lane&31), kv=(reg&3)+8*(reg>>2)+4hl.
// PV: O^T[d][q] = mfma(A=Vt-rows, B=P^T); V stored with kv bits 2<->3 swapped so
// QK C-regs ARE the PV B-fragment in identity order.
// Staging: 4 global_load_lds per wave per tile into the inactive buffer,
// pre-swizzled source slot (lane&7)^(lane>>3); one __syncthreads per tile.
__global__ __launch_bounds__(256, 3) void attn_kernel(
    const unsigned short* __restrict__ Qb, const unsigned short* __restrict__ Kb,
    const unsigned short* __restrict__ Vt, unsigned short* __restrict__ Cv) {
  __shared__ unsigned short lds_k[2][64 * 64];   // [kv][d] swizzled
  __shared__ unsigned short lds_v[2][64 * 64];   // [d][kv-permuted] swizzled
  int tid = threadIdx.x;
  int wave = tid >> 6, lane = tid & 63;
  int q31 = lane & 31, hl = lane >> 5;
  int bh = blockIdx.x, qt = blockIdx.y;
  int b = bh >> 4, h = bh & 15;

  int rl = lane >> 3;                       // row within 8-row group
  int xsl = ((lane & 7) ^ rl) << 3;         // pre-swizzled slot offset (halves)
  // per-lane global staging bases (row group = wave*16 + u*8)
  const unsigned short* kg = &Kb[(size_t)(b * SQL + wave * 16 + rl) * DM + h * 64 + xsl];
  const unsigned short* vg = &Vt[((size_t)(bh * 64) + wave * 16 + rl) * SQL + xsl];

  // Q fragments: B-operand per kstep s: lane holds Q[q31][s*16 + hl*8 + 0..7]
  bf16x8 qf[4];
  int gr = b * SQL + qt * 128 + wave * 32 + q31;
#pragma unroll
  for (int s = 0; s < 4; s++)
    qf[s] = *(const bf16x8*)&Qb[(size_t)gr * DM + h * 64 + s * 16 + hl * 8];

  const floatx16 fz16 = {0.f, 0.f, 0.f, 0.f, 0.f, 0.f, 0.f, 0.f,
                         0.f, 0.f, 0.f, 0.f, 0.f, 0.f, 0.f, 0.f};
  floatx16 o[2];  // O^T accum per d-tile: col=q31, row d=(reg&3)+8*(reg>>2)+4hl+32*dt
  o[0] = fz16; o[1] = fz16;
  float l_ = 0.f;

  // prologue: stage tile 0
#pragma unroll
  for (int u = 0; u < 2; u++) {
    GLD(kg + (size_t)(u * 8) * DM, &lds_k[0][(wave * 16 + u * 8) << 6]);
    GLD(vg + (size_t)(u * 8) * SQL, &lds_v[0][(wave * 16 + u * 8) << 6]);
  }
  __syncthreads();

#pragma unroll 1
  for (int t = 0; t < 32; t++) {
    int cur = t & 1, nxt = cur ^ 1;
    if (t + 1 < 32) {
      size_t koff = (size_t)((t + 1) * 64) * DM;
      size_t voff = (size_t)((t + 1) * 64);
#pragma unroll
      for (int u = 0; u < 2; u++) {
        GLD(kg + koff + (size_t)(u * 8) * DM, &lds_k[nxt][(wave * 16 + u * 8) << 6]);
        GLD(vg + voff + (size_t)(u * 8) * SQL, &lds_v[nxt][(wave * 16 + u * 8) << 6]);
      }
    }

    // ---- QK^T: st[j] over kv-tile j
    floatx16 st[2];
    __builtin_amdgcn_s_setprio(1);
#pragma unroll
    for (int j = 0; j < 2; j++) {
      bf16x8 kf = *(const bf16x8*)&lds_k[cur][SW(j * 32 + q31, hl)];
      st[j] = __builtin_amdgcn_mfma_f32_32x32x16_bf16(kf, qf[0], fz16, 0, 0, 0);
    }
#pragma unroll
    for (int s = 1; s < 4; s++)
#pragma unroll
      for (int j = 0; j < 2; j++) {
        bf16x8 kf = *(const bf16x8*)&lds_k[cur][SW(j * 32 + q31, 2 * s + hl)];
        st[j] = __builtin_amdgcn_mfma_f32_32x32x16_bf16(kf, qf[s], st[j], 0, 0, 0);
      }
    __builtin_amdgcn_s_setprio(0);

    // ---- softmax: exp2 in place, 4 partial sum chains
#pragma unroll
    for (int j = 0; j < 2; j++)
#pragma unroll
      for (int r = 0; r < 16; r++) st[j][r] = __builtin_amdgcn_exp2f(st[j][r]);
    float p0 = 0.f, p1 = 0.f, p2 = 0.f, p3 = 0.f;
#pragma unroll
    for (int r = 0; r < 16; r += 2) {
      p0 += st[0][r]; p1 += st[0][r + 1];
      p2 += st[1][r]; p3 += st[1][r + 1];
    }
    l_ += (p0 + p1) + (p2 + p3);

    // pack P: B-fragment for PV step (j, s2) = C-regs s2*8..s2*8+7 (identity order)
    bf16x8 pb[2][2];
#pragma unroll
    for (int j = 0; j < 2; j++)
#pragma unroll
      for (int s2 = 0; s2 < 2; s2++) {
        bf16x8 r;
#pragma unroll
        for (int e = 0; e < 8; e++) r[e] = (__bf16)st[j][s2 * 8 + e];
        pb[j][s2] = r;
      }

    // ---- PV: o[dt] over d-tile dt
    __builtin_amdgcn_s_setprio(1);
#pragma unroll
    for (int dt = 0; dt < 2; dt++)
#pragma unroll
      for (int j = 0; j < 2; j++)
#pragma unroll
        for (int s2 = 0; s2 < 2; s2++) {
          bf16x8 av = *(const bf16x8*)&lds_v[cur][SW(dt * 32 + q31, j * 4 + s2 * 2 + hl)];
          o[dt] = __builtin_amdgcn_mfma_f32_32x32x16_bf16(av, pb[j][s2], o[dt], 0, 0, 0);
        }
    __builtin_amdgcn_s_setprio(0);

    __syncthreads();
  }

  l_ += __shfl_xor(l_, 32);
  float inv = 1.f / l_;
#pragma unroll
  for (int dt = 0; dt < 2; dt++)
#pragma unroll
    for (int g = 0; g < 4; g++) {
      bf16x4 ov;
      ov[0] = (__bf16)(o[dt][4 * g + 0] * inv);
      ov[1] = (__bf16)(o[dt][4 * g + 1] * inv);
      ov[2] = (__bf16)(o[dt][4 * g + 2] * inv);
      ov[3] = (__bf16)(o[dt][4 * g + 3] * inv);
      int d0 = dt * 32 + g * 8 + hl * 4;
      *(bf16x4*)&Cv[(size_t)gr * DM + h * 64 + d0] = ov;
    }
}

extern "C" void kernel_launch(void* const* d_in, const int* in_sizes, int n_in,
                              void* d_out, int out_size, void* d_ws, size_t ws_size,
                              hipStream_t stream) {
  const float* q  = (const float*)d_in[0];
  const float* k  = (const float*)d_in[1];
  const float* v  = (const float*)d_in[2];
  const float* wq = (const float*)d_in[3];
  const float* bq = (const float*)d_in[4];
  const float* wk = (const float*)d_in[5];
  const float* bk = (const float*)d_in[6];
  const float* wv = (const float*)d_in[7];
  const float* bv = (const float*)d_in[8];
  const float* wo = (const float*)d_in[9];
  const float* bo = (const float*)d_in[10];
  float* out = (float*)d_out;

  char* ws = (char*)d_ws;
  unsigned short* wqt = (unsigned short*)(ws + (size_t)0);
  unsigned short* wkt = (unsigned short*)(ws + ((size_t)2 << 20));
  unsigned short* wvt = (unsigned short*)(ws + ((size_t)4 << 20));
  unsigned short* wot = (unsigned short*)(ws + ((size_t)6 << 20));
  unsigned short* Qb  = (unsigned short*)(ws + ((size_t)8 << 20));
  unsigned short* Kb  = (unsigned short*)(ws + ((size_t)24 << 20));
  unsigned short* Vt  = (unsigned short*)(ws + ((size_t)40 << 20));
  unsigned short* Cv  = (unsigned short*)(ws + ((size_t)56 << 20));
  // bf16-A scratch: d_out (32 MiB, rewritten by gemm_out at the end) holds q,k; Cv holds v.
  unsigned short* Aq = (unsigned short*)d_out;
  unsigned short* Ak = (unsigned short*)d_out + ((size_t)8 << 20);
  unsigned short* Av = Cv;

  const float QSCALE = 0.125f * 1.44269504088896340736f;  // 1/sqrt(64) * log2(e)

  dim3 blk(256);
  prep_kernel<<<dim3(4096), blk, 0, stream>>>(q, k, v, Aq, Ak, Av,
                                              wq, wk, wv, wo, wqt, wkt, wvt, wot);
  gemm_qkv_kernel<<<dim3(8, 32, 3), dim3(512), 0, stream>>>(Aq, Ak, Av, wqt, wkt, wvt,
                                                            bq, bk, bv, Qb, Kb, Vt, QSCALE);
  attn_kernel<<<dim3(64, 16), blk, 0, stream>>>(Qb, Kb, Vt, Cv);
  gemm_out_kernel<<<dim3(8, 32), dim3(512), 0, stream>>>(Cv, wot, bo, out);
}